// Round 1
// baseline (3033.801 us; speedup 1.0000x reference)
//
#include <hip/hip_runtime.h>
#include <hip/hip_bf16.h>
#include <cstdint>

#define B_  8
#define T_  16
#define HIN 640
#define WIN 480
#define HP  320
#define WP  240
#define HO  318
#define WO  238
#define F_  16
#define G_  64

#define TX 16
#define TY 16
#define CP 17   // channel pad (odd) -> ~2-way LDS conflict on h reads

__device__ __forceinline__ float hsg(float v) {
    return fminf(fmaxf(fmaf(v, 0.2f, 0.5f), 0.0f), 1.0f);
}

__device__ __forceinline__ void fma4(float4& a, float s, const float4 w) {
    a.x = fmaf(s, w.x, a.x);
    a.y = fmaf(s, w.y, a.y);
    a.z = fmaf(s, w.z, a.z);
    a.w = fmaf(s, w.w, a.w);
}

// MaxPool (1,2,2): in (B,T,640,480) -> out (B,T,320,240). 2 outputs/thread.
__global__ void pool_kernel(const float* __restrict__ in, float* __restrict__ out) {
    int idx = blockIdx.x * 256 + threadIdx.x;
    const int total = B_ * T_ * HP * (WP / 2);
    if (idx >= total) return;
    int xp   = idx % (WP / 2);
    int rest = idx / (WP / 2);
    int y    = rest % HP;
    int bt   = rest / HP;
    const float* src = in + ((size_t)bt * HIN + 2 * y) * WIN + xp * 4;
    float4 a = *(const float4*)src;
    float4 b = *(const float4*)(src + WIN);
    float m0 = fmaxf(fmaxf(a.x, a.y), fmaxf(b.x, b.y));
    float m1 = fmaxf(fmaxf(a.z, a.w), fmaxf(b.z, b.w));
    *(float2*)(out + ((size_t)bt * HP + y) * WP + xp * 2) = make_float2(m0, m1);
}

// Fused: z = conv_valid(x_t, kin) + bias + conv_same(h_prev, krec); gates; c,h update.
// Block: 256 threads, 16x16 pixel tile. Thread = (cg = gate-channel quartet 0..3) x
// (64 pixel-slots: x = lane%16, rows row0..row0+3). Each thread: 4 pixels x
// {i,f,c,o} x 4 channels -> gate math fully thread-local.
__global__ __launch_bounds__(256, 2)
void lstm_step_kernel(const float* __restrict__ xp, int t,
                      const float* __restrict__ hprev,
                      const float* __restrict__ cprev,
                      float* __restrict__ cout,
                      float* __restrict__ hout,
                      const float* __restrict__ kin,
                      const float* __restrict__ krec,
                      const float* __restrict__ bias) {
    __shared__ float sh_h[TY + 2][TX + 2][CP];  // 22032 B
    __shared__ float sh_w[9 * 16 * 64];         // 36864 B
    __shared__ float sh_x[TY + 2][TX + 3];      // 1368 B
    __shared__ float sh_k[9 * 64];              // 2304 B

    const int tid  = threadIdx.x;
    const int cg   = tid >> 6;          // gate-channel quartet (channels cg*4..cg*4+3)
    const int pg   = tid & 63;
    const int x    = pg & 15;           // in-tile x
    const int row0 = (pg >> 4) << 2;    // in-tile y base (4 rows per thread)
    const int b    = blockIdx.z;
    const int x0   = blockIdx.x * TX;
    const int y0   = blockIdx.y * TY;

    // stage weights
    {
        const float4* src = (const float4*)krec;   // 9216 floats = 2304 float4
        float4* dst = (float4*)sh_w;
        #pragma unroll
        for (int i = 0; i < 9; ++i) dst[tid + i * 256] = src[tid + i * 256];
        if (tid < 144) ((float4*)sh_k)[tid] = ((const float4*)kin)[tid];
    }
    // stage pooled-x tile (valid conv: rows y0..y0+17)
    {
        const float* xsrc = xp + ((size_t)b * T_ + t) * (HP * WP);
        for (int i = tid; i < (TY + 2) * (TX + 2); i += 256) {
            int ry = i / (TX + 2), rx = i % (TX + 2);
            int gy = y0 + ry, gx = x0 + rx;
            sh_x[ry][rx] = (gy < HP && gx < WP) ? xsrc[(size_t)gy * WP + gx] : 0.0f;
        }
    }
    // stage h tile with SAME-padding halo (rows y0-1..y0+16)
    {
        for (int i = tid; i < (TY + 2) * (TX + 2) * 4; i += 256) {
            int pix = i >> 2;
            int c4  = (i & 3) * 4;
            int ry = pix / (TX + 2), rx = pix % (TX + 2);
            int gy = y0 + ry - 1, gx = x0 + rx - 1;
            float4 v = make_float4(0.f, 0.f, 0.f, 0.f);
            if (gy >= 0 && gy < HO && gx >= 0 && gx < WO)
                v = *(const float4*)&hprev[(((size_t)b * HO + gy) * WO + gx) * F_ + c4];
            sh_h[ry][rx][c4 + 0] = v.x;
            sh_h[ry][rx][c4 + 1] = v.y;
            sh_h[ry][rx][c4 + 2] = v.z;
            sh_h[ry][rx][c4 + 3] = v.w;
        }
    }
    __syncthreads();

    float4 acc[4][4];   // [pixel j][gate type]; channels = cg*4..cg*4+3
    {
        const float4 b0 = *(const float4*)&bias[0 * F_ + cg * 4];
        const float4 b1 = *(const float4*)&bias[1 * F_ + cg * 4];
        const float4 b2 = *(const float4*)&bias[2 * F_ + cg * 4];
        const float4 b3 = *(const float4*)&bias[3 * F_ + cg * 4];
        #pragma unroll
        for (int j = 0; j < 4; ++j) { acc[j][0] = b0; acc[j][1] = b1; acc[j][2] = b2; acc[j][3] = b3; }
    }

    // input conv (1 channel)
    #pragma unroll
    for (int dy = 0; dy < 3; ++dy) {
        #pragma unroll
        for (int dx = 0; dx < 3; ++dx) {
            const float* wp = &sh_k[(dy * 3 + dx) * G_ + cg * 4];
            float4 w0 = *(const float4*)(wp + 0);
            float4 w1 = *(const float4*)(wp + 16);
            float4 w2 = *(const float4*)(wp + 32);
            float4 w3 = *(const float4*)(wp + 48);
            #pragma unroll
            for (int j = 0; j < 4; ++j) {
                float xv = sh_x[row0 + j + dy][x + dx];
                fma4(acc[j][0], xv, w0);
                fma4(acc[j][1], xv, w1);
                fma4(acc[j][2], xv, w2);
                fma4(acc[j][3], xv, w3);
            }
        }
    }

    // recurrent conv (16 channels, SAME)
    for (int kk = 0; kk < 9; ++kk) {
        const int dy = kk / 3, dx = kk % 3;
        #pragma unroll
        for (int ci = 0; ci < 16; ++ci) {
            const float* wp = &sh_w[(kk * 16 + ci) * G_ + cg * 4];
            float4 w0 = *(const float4*)(wp + 0);    // i
            float4 w1 = *(const float4*)(wp + 16);   // f
            float4 w2 = *(const float4*)(wp + 32);   // c
            float4 w3 = *(const float4*)(wp + 48);   // o
            #pragma unroll
            for (int j = 0; j < 4; ++j) {
                float hv = sh_h[row0 + j + dy][x + dx][ci];
                fma4(acc[j][0], hv, w0);
                fma4(acc[j][1], hv, w1);
                fma4(acc[j][2], hv, w2);
                fma4(acc[j][3], hv, w3);
            }
        }
    }

    // gates + state update
    const int xo = x0 + x;
    if (xo < WO) {
        #pragma unroll
        for (int j = 0; j < 4; ++j) {
            int yo = y0 + row0 + j;
            if (yo < HO) {
                size_t base = (((size_t)b * HO + yo) * WO + xo) * F_ + cg * 4;
                float4 cold = *(const float4*)&cprev[base];
                float4 cn, hn;
                #define GATE(K, C) { \
                    float zi = acc[j][0].C, zf = acc[j][1].C, zc = acc[j][2].C, zo_ = acc[j][3].C; \
                    float cv = fmaf(hsg(zf), cold.C, hsg(zi) * tanhf(zc)); \
                    cn.C = cv; hn.C = hsg(zo_) * tanhf(cv); }
                GATE(0, x) GATE(1, y) GATE(2, z) GATE(3, w)
                #undef GATE
                *(float4*)&cout[base] = cn;
                *(float4*)&hout[base] = hn;
            }
        }
    }
}

#define FLATN (HO * WO * F_)                      // 1210944 (divisible by 16)
#define CHUNK 4096
#define NCHUNK ((FLATN + CHUNK - 1) / CHUNK)      // 296

__global__ void dense1_kernel(const float* __restrict__ h, const float* __restrict__ w,
                              float* __restrict__ partial) {
    int b = blockIdx.y;
    int tid = threadIdx.x;
    size_t off = (size_t)blockIdx.x * CHUNK + (size_t)tid * 16;
    const float* hb = h + (size_t)b * FLATN;
    float s = 0.0f;
    if (off < (size_t)FLATN) {
        #pragma unroll
        for (int q = 0; q < 4; ++q) {
            float4 hv = *(const float4*)&hb[off + q * 4];
            float4 wv = *(const float4*)&w[off + q * 4];
            s += hv.x * wv.x + hv.y * wv.y + hv.z * wv.z + hv.w * wv.w;
        }
    }
    #pragma unroll
    for (int o = 32; o > 0; o >>= 1) s += __shfl_down(s, o, 64);
    __shared__ float red[4];
    if ((tid & 63) == 0) red[tid >> 6] = s;
    __syncthreads();
    if (tid == 0) partial[b * NCHUNK + blockIdx.x] = red[0] + red[1] + red[2] + red[3];
}

__global__ void dense2_kernel(const float* __restrict__ partial, const float* __restrict__ db,
                              float* __restrict__ out) {
    int b = blockIdx.x;
    int tid = threadIdx.x;
    float s = 0.0f;
    for (int i = tid; i < NCHUNK; i += 256) s += partial[b * NCHUNK + i];
    #pragma unroll
    for (int o = 32; o > 0; o >>= 1) s += __shfl_down(s, o, 64);
    __shared__ float red[4];
    if ((tid & 63) == 0) red[tid >> 6] = s;
    __syncthreads();
    if (tid == 0) out[b] = red[0] + red[1] + red[2] + red[3] + db[0];
}

extern "C" void kernel_launch(void* const* d_in, const int* in_sizes, int n_in,
                              void* d_out, int out_size, void* d_ws, size_t ws_size,
                              hipStream_t stream) {
    const float* inputs = (const float*)d_in[0];
    const float* kin    = (const float*)d_in[1];
    const float* krec   = (const float*)d_in[2];
    const float* bias   = (const float*)d_in[3];
    const float* dw     = (const float*)d_in[4];
    const float* db     = (const float*)d_in[5];
    float* out = (float*)d_out;

    float* ws = (float*)d_ws;
    const size_t XPN = (size_t)B_ * T_ * HP * WP;   // 9,830,400 floats
    const size_t HN  = (size_t)B_ * HO * WO * F_;   // 9,687,552 floats
    float* xp   = ws;
    float* h0   = xp + XPN;
    float* h1   = h0 + HN;
    float* cbuf = h1 + HN;
    float* part = cbuf + HN;                        // 2368 floats; total ~156 MB

    hipMemsetAsync(h0, 0, HN * sizeof(float), stream);
    hipMemsetAsync(cbuf, 0, HN * sizeof(float), stream);

    {
        int total = B_ * T_ * HP * (WP / 2);
        pool_kernel<<<(total + 255) / 256, 256, 0, stream>>>(inputs, xp);
    }

    dim3 cgrid((WO + TX - 1) / TX, (HO + TY - 1) / TY, B_);   // 15 x 20 x 8
    for (int t = 0; t < T_; ++t) {
        const float* hp = (t & 1) ? h1 : h0;
        float* hn       = (t & 1) ? h0 : h1;
        lstm_step_kernel<<<cgrid, 256, 0, stream>>>(xp, t, hp, cbuf, cbuf, hn, kin, krec, bias);
    }
    // t=15 (odd) wrote h0 -> final h is h0
    dense1_kernel<<<dim3(NCHUNK, B_), 256, 0, stream>>>(h0, dw, part);
    dense2_kernel<<<8, 256, 0, stream>>>(part, db, out);
}

// Round 2
// 1315.732 us; speedup vs baseline: 2.3058x; 2.3058x over previous
//
#include <hip/hip_runtime.h>
#include <hip/hip_bf16.h>
#include <cstdint>

#define B_  8
#define T_  16
#define HIN 640
#define WIN 480
#define HP  320
#define WP  240
#define HO  318
#define WO  238

typedef unsigned short u16;
typedef unsigned int   u32;
typedef __attribute__((ext_vector_type(8))) short bf16x8;
typedef __attribute__((ext_vector_type(4))) float f32x4;

#define CIP 24              // LDS pixel pitch in halfwords (48 B: 16B-aligned b128, 2-way banks)
#define PL  (4 * 66 * CIP)  // plane stride (halfwords)

__device__ __forceinline__ u16 f2bf(float f) {          // RNE float->bf16 bits
    u32 u = __float_as_uint(f);
    return (u16)((u + 0x7fffu + ((u >> 16) & 1u)) >> 16);
}
__device__ __forceinline__ float bf2f(u16 u) {
    return __uint_as_float(((u32)u) << 16);
}
__device__ __forceinline__ float hsg(float v) {
    return fminf(fmaxf(fmaf(v, 0.2f, 0.5f), 0.0f), 1.0f);
}
__device__ __forceinline__ float tanh_fast(float x) {
    float ax = fminf(fabsf(x), 12.0f);
    float e  = __expf(2.0f * ax);
    float t  = 1.0f - __fdividef(2.0f, e + 1.0f);
    return copysignf(t, x);
}

// ---------------- MaxPool (1,2,2) ----------------
__global__ void pool_kernel(const float* __restrict__ in, float* __restrict__ out) {
    int idx = blockIdx.x * 256 + threadIdx.x;
    const int total = B_ * T_ * HP * (WP / 2);
    if (idx >= total) return;
    int xp   = idx % (WP / 2);
    int rest = idx / (WP / 2);
    int y    = rest % HP;
    int bt   = rest / HP;
    const float* src = in + ((size_t)bt * HIN + 2 * y) * WIN + xp * 4;
    float4 a = *(const float4*)src;
    float4 b = *(const float4*)(src + WIN);
    float m0 = fmaxf(fmaxf(a.x, a.y), fmaxf(b.x, b.y));
    float m1 = fmaxf(fmaxf(a.z, a.w), fmaxf(b.z, b.w));
    *(float2*)(out + ((size_t)bt * HP + y) * WP + xp * 2) = make_float2(m0, m1);
}

// ---------------- weight fragment pre-pack ----------------
// K layout: k = tap*16+ci (k<144, recurrent), k = 144+xtap (k<153, input conv), else 0.
// frag_id = (q*4 + nt)*2 + plane(hi=0/lo=1); record = [64 lanes][16 B].
// B-frag (16x16x32): lane l holds W[k = q*32 + (l>>4)*8 + j][n = nt*16 + (l&15)], j=0..7.
__global__ void frag_build(const float* __restrict__ krec, const float* __restrict__ kin,
                           int4* __restrict__ fragbuf) {
    int idx = blockIdx.x * 256 + threadIdx.x;
    if (idx >= 40 * 64) return;
    int l = idx & 63, frag = idx >> 6;
    int plane = frag & 1, nt = (frag >> 1) & 3, q = frag >> 3;
    int n = nt * 16 + (l & 15), o = l >> 4;
    u16 u[8];
    #pragma unroll
    for (int j = 0; j < 8; ++j) {
        int k = q * 32 + o * 8 + j;
        float wv = 0.0f;
        if (k < 144) wv = krec[k * 64 + n];           // (3,3,16,64) flat == k*64+n
        else if (k < 153) wv = kin[(k - 144) * 64 + n];
        u16 hi = f2bf(wv);
        u[j] = plane ? f2bf(wv - bf2f(hi)) : hi;
    }
    int4 v;
    v.x = (int)((u32)u[0] | ((u32)u[1] << 16));
    v.y = (int)((u32)u[2] | ((u32)u[3] << 16));
    v.z = (int)((u32)u[4] | ((u32)u[5] << 16));
    v.w = (int)((u32)u[6] | ((u32)u[7] << 16));
    fragbuf[frag * 64 + l] = v;
}

// ---------------- fused ConvLSTM step (implicit GEMM, MFMA) ----------------
// Block: 128 pixels (2 rows x 64 x) x N=64. 4 waves; wave w owns x-range w*16..+15 of
// both rows, all 4 gate N-tiles -> gates thread-local in C layout.
__global__ __launch_bounds__(256, 2)
void lstm_step(const float* __restrict__ xp, int t,
               const u16* __restrict__ hhi, const u16* __restrict__ hlo,
               u16* __restrict__ hhi_o, u16* __restrict__ hlo_o,
               float* __restrict__ cbuf,
               const int4* __restrict__ fragbuf,
               const float* __restrict__ bias) {
    __shared__ u16  sh[2 * PL];     // h halo: [plane][4 rows][66 x][24 pitch] bf16
    __shared__ float sx[4 * 66];    // pooled-x tile fp32

    const int tid = threadIdx.x;
    const int wv_ = tid >> 6;
    const int l   = tid & 63;
    const int b   = blockIdx.z;
    const int y0  = blockIdx.y * 2;
    const int x0  = blockIdx.x * 64;

    // B fragments (L2-hot) + bias
    bf16x8 Bh[5][4], Bl[5][4];
    #pragma unroll
    for (int q = 0; q < 5; ++q)
        #pragma unroll
        for (int nt = 0; nt < 4; ++nt) {
            int4 th = fragbuf[((q * 4 + nt) * 2 + 0) * 64 + l];
            int4 tl = fragbuf[((q * 4 + nt) * 2 + 1) * 64 + l];
            Bh[q][nt] = __builtin_bit_cast(bf16x8, th);
            Bl[q][nt] = __builtin_bit_cast(bf16x8, tl);
        }
    float bv[4];
    #pragma unroll
    for (int nt = 0; nt < 4; ++nt) bv[nt] = bias[nt * 16 + (l & 15)];

    // stage h halo (hi+lo planes); t==0 -> zeros (skip memset entirely)
    for (int i = tid; i < 264; i += 256) {
        int hr = i / 66, hx = i % 66;
        int gy = y0 - 1 + hr, gx = x0 - 1 + hx;
        bool ok = (t > 0) && (gy >= 0) && (gy < HO) && (gx >= 0) && (gx < WO);
        int off = (hr * 66 + hx) * CIP;
        int4 z = make_int4(0, 0, 0, 0);
        int4 a0 = z, a1 = z, c0 = z, c1 = z;
        if (ok) {
            size_t g = (((size_t)b * HO + gy) * WO + gx) * 16;
            a0 = *(const int4*)&hhi[g]; a1 = *(const int4*)&hhi[g + 8];
            c0 = *(const int4*)&hlo[g]; c1 = *(const int4*)&hlo[g + 8];
        }
        *(int4*)&sh[off] = a0;      *(int4*)&sh[off + 8] = a1;
        *(int4*)&sh[PL + off] = c0; *(int4*)&sh[PL + off + 8] = c1;
    }
    // stage x tile (valid-conv window rows y0..y0+3, cols x0..x0+65)
    {
        const float* xs = xp + ((size_t)(b * T_ + t) * HP) * WP;
        for (int i = tid; i < 264; i += 256) {
            int xr = i / 66, xc = i % 66;
            int gx = x0 + xc;
            sx[i] = (gx < WP) ? xs[(size_t)(y0 + xr) * WP + gx] : 0.0f;
        }
    }
    __syncthreads();

    f32x4 acc[2][4];
    #pragma unroll
    for (int m = 0; m < 2; ++m)
        #pragma unroll
        for (int nt = 0; nt < 4; ++nt)
            acc[m][nt] = (f32x4){bv[nt], bv[nt], bv[nt], bv[nt]};

    const int xl    = l & 15;
    const int ci0   = ((l >> 4) & 1) * 8;
    const int baseA = (wv_ * 16 + xl) * CIP + ci0;
    const bool hiH  = (l >= 32);

    // chunks 0..3: pure recurrent taps (tap = 2q + (l>=32))
    #pragma unroll
    for (int q = 0; q < 4; ++q) {
        const int tapA = 2 * q, tapB = 2 * q + 1;
        #pragma unroll
        for (int m = 0; m < 2; ++m) {
            const int cA = ((m + tapA / 3) * 66 + (tapA % 3)) * CIP;
            const int cB = ((m + tapB / 3) * 66 + (tapB % 3)) * CIP;
            const int c  = hiH ? cB : cA;
            bf16x8 Ah = *(const bf16x8*)&sh[baseA + c];
            bf16x8 Al = *(const bf16x8*)&sh[PL + baseA + c];
            #pragma unroll
            for (int nt = 0; nt < 4; ++nt) {
                acc[m][nt] = __builtin_amdgcn_mfma_f32_16x16x32_bf16(Ah, Bh[q][nt], acc[m][nt], 0, 0, 0);
                acc[m][nt] = __builtin_amdgcn_mfma_f32_16x16x32_bf16(Ah, Bl[q][nt], acc[m][nt], 0, 0, 0);
                acc[m][nt] = __builtin_amdgcn_mfma_f32_16x16x32_bf16(Al, Bh[q][nt], acc[m][nt], 0, 0, 0);
            }
        }
    }
    // chunk 4: lanes<32 = h tap8 (dy=dx=2); lanes 32..47 = x taps 0..7; 48..63 = x tap 8 + zeros.
    // x lives only in Ahi (Alo=0 there) so passes give x*whi + x*wlo exactly once each.
    #pragma unroll
    for (int m = 0; m < 2; ++m) {
        bf16x8 Ah, Al;
        if (!hiH) {
            const int c8 = ((m + 2) * 66 + 2) * CIP;
            Ah = *(const bf16x8*)&sh[baseA + c8];
            Al = *(const bf16x8*)&sh[PL + baseA + c8];
        } else {
            const int xb = wv_ * 16 + xl;
            u16 u[8];
            if (l < 48) {
                #pragma unroll
                for (int j = 0; j < 8; ++j)
                    u[j] = f2bf(sx[(m + j / 3) * 66 + xb + (j % 3)]);
            } else {
                u[0] = f2bf(sx[(m + 2) * 66 + xb + 2]);
                #pragma unroll
                for (int j = 1; j < 8; ++j) u[j] = 0;
            }
            int4 p;
            p.x = (int)((u32)u[0] | ((u32)u[1] << 16));
            p.y = (int)((u32)u[2] | ((u32)u[3] << 16));
            p.z = (int)((u32)u[4] | ((u32)u[5] << 16));
            p.w = (int)((u32)u[6] | ((u32)u[7] << 16));
            Ah = __builtin_bit_cast(bf16x8, p);
            Al = __builtin_bit_cast(bf16x8, make_int4(0, 0, 0, 0));
        }
        #pragma unroll
        for (int nt = 0; nt < 4; ++nt) {
            acc[m][nt] = __builtin_amdgcn_mfma_f32_16x16x32_bf16(Ah, Bh[4][nt], acc[m][nt], 0, 0, 0);
            acc[m][nt] = __builtin_amdgcn_mfma_f32_16x16x32_bf16(Ah, Bl[4][nt], acc[m][nt], 0, 0, 0);
            acc[m][nt] = __builtin_amdgcn_mfma_f32_16x16x32_bf16(Al, Bh[4][nt], acc[m][nt], 0, 0, 0);
        }
    }

    // gates + state update. C layout: col = l&15 (channel), row = (l>>4)*4 + r (x offset).
    #pragma unroll
    for (int m = 0; m < 2; ++m) {
        const int y = y0 + m;
        #pragma unroll
        for (int r = 0; r < 4; ++r) {
            const int x = x0 + wv_ * 16 + (l >> 4) * 4 + r;
            if (x < WO) {
                size_t g = (((size_t)b * HO + y) * WO + x) * 16 + (l & 15);
                float co = (t > 0) ? cbuf[g] : 0.0f;
                float zi = acc[m][0][r], zf = acc[m][1][r], zc = acc[m][2][r], zo = acc[m][3][r];
                float cn = fmaf(hsg(zf), co, hsg(zi) * tanh_fast(zc));
                float hn = hsg(zo) * tanh_fast(cn);
                cbuf[g] = cn;
                u16 uhi = f2bf(hn);
                hhi_o[g] = uhi;
                hlo_o[g] = f2bf(hn - bf2f(uhi));
            }
        }
    }
}

// ---------------- dense ----------------
#define FLATN (HO * WO * 16)
#define NCHUNK ((FLATN + 4095) / 4096)

__device__ __forceinline__ float dotbf(u32 a, u32 c, const float* wp, float s) {
    float h0 = __uint_as_float(a << 16)          + __uint_as_float(c << 16);
    float h1 = __uint_as_float(a & 0xFFFF0000u)  + __uint_as_float(c & 0xFFFF0000u);
    s = fmaf(h0, wp[0], s);
    return fmaf(h1, wp[1], s);
}

__global__ void dense1(const u16* __restrict__ hhi, const u16* __restrict__ hlo,
                       const float* __restrict__ w, float* __restrict__ partial) {
    int b = blockIdx.y, tid = threadIdx.x;
    size_t off = (size_t)blockIdx.x * 4096 + (size_t)tid * 16;
    float s = 0.0f;
    if (off < (size_t)FLATN) {
        const u16* ph = hhi + (size_t)b * FLATN + off;
        const u16* pl = hlo + (size_t)b * FLATN + off;
        int4 va = *(const int4*)&ph[0], vb = *(const int4*)&ph[8];
        int4 vc = *(const int4*)&pl[0], vd = *(const int4*)&pl[8];
        const float* wp = &w[off];
        s = dotbf((u32)va.x, (u32)vc.x, wp + 0,  s);
        s = dotbf((u32)va.y, (u32)vc.y, wp + 2,  s);
        s = dotbf((u32)va.z, (u32)vc.z, wp + 4,  s);
        s = dotbf((u32)va.w, (u32)vc.w, wp + 6,  s);
        s = dotbf((u32)vb.x, (u32)vd.x, wp + 8,  s);
        s = dotbf((u32)vb.y, (u32)vd.y, wp + 10, s);
        s = dotbf((u32)vb.z, (u32)vd.z, wp + 12, s);
        s = dotbf((u32)vb.w, (u32)vd.w, wp + 14, s);
    }
    #pragma unroll
    for (int o = 32; o > 0; o >>= 1) s += __shfl_down(s, o, 64);
    __shared__ float red[4];
    if ((tid & 63) == 0) red[tid >> 6] = s;
    __syncthreads();
    if (tid == 0) partial[b * NCHUNK + blockIdx.x] = red[0] + red[1] + red[2] + red[3];
}

__global__ void dense2(const float* __restrict__ partial, const float* __restrict__ db,
                       float* __restrict__ out) {
    int b = blockIdx.x, tid = threadIdx.x;
    float s = 0.0f;
    for (int i = tid; i < NCHUNK; i += 256) s += partial[b * NCHUNK + i];
    #pragma unroll
    for (int o = 32; o > 0; o >>= 1) s += __shfl_down(s, o, 64);
    __shared__ float red[4];
    if ((tid & 63) == 0) red[tid >> 6] = s;
    __syncthreads();
    if (tid == 0) out[b] = red[0] + red[1] + red[2] + red[3] + db[0];
}

extern "C" void kernel_launch(void* const* d_in, const int* in_sizes, int n_in,
                              void* d_out, int out_size, void* d_ws, size_t ws_size,
                              hipStream_t stream) {
    const float* inputs = (const float*)d_in[0];
    const float* kin    = (const float*)d_in[1];
    const float* krec   = (const float*)d_in[2];
    const float* bias   = (const float*)d_in[3];
    const float* dw     = (const float*)d_in[4];
    const float* db     = (const float*)d_in[5];
    float* out = (float*)d_out;

    const size_t XPN = (size_t)B_ * T_ * HP * WP;    // 9,830,400 floats
    const size_t HN  = (size_t)B_ * HO * WO * 16;    // 9,687,552 elems

    float* xp   = (float*)d_ws;
    u16*  h0hi  = (u16*)(xp + XPN);
    u16*  h0lo  = h0hi + HN;
    u16*  h1hi  = h0lo + HN;
    u16*  h1lo  = h1hi + HN;
    float* cbuf = (float*)(h1lo + HN);
    int4*  frag = (int4*)(cbuf + HN);                // 40 KB
    float* part = (float*)(frag + 40 * 64);

    {
        int total = B_ * T_ * HP * (WP / 2);
        pool_kernel<<<(total + 255) / 256, 256, 0, stream>>>(inputs, xp);
    }
    frag_build<<<10, 256, 0, stream>>>(krec, kin, frag);

    dim3 grid(4, 159, B_);   // x-tiles(64) x y-tiles(2 rows) x batch
    for (int t = 0; t < T_; ++t) {
        const u16 *ihi, *ilo;
        u16 *ohi, *olo;
        if ((t & 1) == 0) { ihi = h0hi; ilo = h0lo; ohi = h1hi; olo = h1lo; }
        else              { ihi = h1hi; ilo = h1lo; ohi = h0hi; olo = h0lo; }
        lstm_step<<<grid, 256, 0, stream>>>(xp, t, ihi, ilo, ohi, olo, cbuf, frag, bias);
    }
    // t=15 wrote h0 planes
    dense1<<<dim3(NCHUNK, B_), 256, 0, stream>>>(h0hi, h0lo, dw, part);
    dense2<<<B_, 256, 0, stream>>>(part, db, out);
}

// Round 3
// 1144.454 us; speedup vs baseline: 2.6509x; 1.1497x over previous
//
#include <hip/hip_runtime.h>
#include <hip/hip_bf16.h>
#include <cstdint>

#define B_  8
#define T_  16
#define HIN 640
#define WIN 480
#define HP  320
#define WP  240
#define HO  318
#define WO  238

typedef unsigned short u16;
typedef unsigned int   u32;
typedef __attribute__((ext_vector_type(8))) short bf16x8;
typedef __attribute__((ext_vector_type(4))) float f32x4;

#define TY     4
#define HROWS  (TY + 2)
#define HPITCH 40   // halfwords/pixel: 32 data (hi16|lo16) + 8 pad -> 20-dword stride, 2-way banks

__device__ __forceinline__ u16 f2bf(float f) {          // RNE float->bf16 bits
    u32 u = __float_as_uint(f);
    return (u16)((u + 0x7fffu + ((u >> 16) & 1u)) >> 16);
}
__device__ __forceinline__ float bf2f(u16 u) {
    return __uint_as_float(((u32)u) << 16);
}
__device__ __forceinline__ float hsg(float v) {
    return fminf(fmaxf(fmaf(v, 0.2f, 0.5f), 0.0f), 1.0f);
}
__device__ __forceinline__ float tanh_fast(float x) {
    float ax = fminf(fabsf(x), 12.0f);
    float e  = __expf(2.0f * ax);
    float t  = 1.0f - __fdividef(2.0f, e + 1.0f);
    return copysignf(t, x);
}

// ---------------- MaxPool (1,2,2) ----------------
__global__ void pool_kernel(const float* __restrict__ in, float* __restrict__ out) {
    int idx = blockIdx.x * 256 + threadIdx.x;
    const int total = B_ * T_ * HP * (WP / 2);
    if (idx >= total) return;
    int xp   = idx % (WP / 2);
    int rest = idx / (WP / 2);
    int y    = rest % HP;
    int bt   = rest / HP;
    const float* src = in + ((size_t)bt * HIN + 2 * y) * WIN + xp * 4;
    float4 a = *(const float4*)src;
    float4 b = *(const float4*)(src + WIN);
    float m0 = fmaxf(fmaxf(a.x, a.y), fmaxf(b.x, b.y));
    float m1 = fmaxf(fmaxf(a.z, a.w), fmaxf(b.z, b.w));
    *(float2*)(out + ((size_t)bt * HP + y) * WP + xp * 2) = make_float2(m0, m1);
}

// ---------------- weight fragment pre-pack ----------------
// K layout: k = tap*16+ci (k<144, recurrent), k = 144+xtap (k<153, input conv), else 0.
// frag_id = (q*4 + nt)*2 + plane(hi=0/lo=1); record = [64 lanes][16 B].
__global__ void frag_build(const float* __restrict__ krec, const float* __restrict__ kin,
                           int4* __restrict__ fragbuf) {
    int idx = blockIdx.x * 256 + threadIdx.x;
    if (idx >= 40 * 64) return;
    int l = idx & 63, frag = idx >> 6;
    int plane = frag & 1, nt = (frag >> 1) & 3, q = frag >> 3;
    int n = nt * 16 + (l & 15), o = l >> 4;
    u16 u[8];
    #pragma unroll
    for (int j = 0; j < 8; ++j) {
        int k = q * 32 + o * 8 + j;
        float wv = 0.0f;
        if (k < 144) wv = krec[k * 64 + n];
        else if (k < 153) wv = kin[(k - 144) * 64 + n];
        u16 hi = f2bf(wv);
        u[j] = plane ? f2bf(wv - bf2f(hi)) : hi;
    }
    int4 v;
    v.x = (int)((u32)u[0] | ((u32)u[1] << 16));
    v.y = (int)((u32)u[2] | ((u32)u[3] << 16));
    v.z = (int)((u32)u[4] | ((u32)u[5] << 16));
    v.w = (int)((u32)u[6] | ((u32)u[7] << 16));
    fragbuf[frag * 64 + l] = v;
}

// ---------------- fused ConvLSTM step ----------------
// Tile: TY=4 rows x 64 x. 4 waves; wave w owns x-slice w*16..+15, all rows, all 4 gates.
__global__ __launch_bounds__(256, 2)
void lstm_step(const float* __restrict__ xp, int t,
               const u16* __restrict__ hin,    // [b][y][x][32] hi|lo interleaved
               u16* __restrict__ hout,
               float* __restrict__ cbuf,
               const int4* __restrict__ fragbuf,
               const float* __restrict__ bias) {
    __shared__ __align__(16) u16 sh_h[HROWS * 66 * HPITCH];  // 31,680 B
    __shared__ __align__(16) u16 sh_B[40 * 64 * 8];          // 40,960 B
    __shared__ u16 sxu[HROWS * 66];                          // x tile bf16

    const int tid = threadIdx.x;
    const int wv_ = tid >> 6;
    const int l   = tid & 63;
    const int b   = blockIdx.z;
    const int y0  = blockIdx.y * TY;
    const int x0  = blockIdx.x * 64;

    // stage h halo (interleaved hi|lo, 64B/pixel contiguous)
    for (int i = tid; i < HROWS * 66; i += 256) {
        int hr = i / 66, hx = i % 66;
        int gy = y0 - 1 + hr, gx = x0 - 1 + hx;
        bool ok = (t > 0) && gy >= 0 && gy < HO && gx >= 0 && gx < WO;
        int4 z = make_int4(0, 0, 0, 0);
        int4 v0 = z, v1 = z, v2 = z, v3 = z;
        if (ok) {
            const int4* g = (const int4*)&hin[(((size_t)b * HO + gy) * WO + gx) * 32];
            v0 = g[0]; v1 = g[1]; v2 = g[2]; v3 = g[3];
        }
        u16* d = &sh_h[i * HPITCH];
        *(int4*)(d + 0) = v0;  *(int4*)(d + 8) = v1;
        *(int4*)(d + 16) = v2; *(int4*)(d + 24) = v3;
    }
    // stage B fragments (40 KB, shared by all waves)
    for (int i = tid; i < 40 * 64; i += 256)
        ((int4*)sh_B)[i] = fragbuf[i];
    // stage x tile as bf16
    {
        const float* xs = xp + ((size_t)(b * T_ + t) * HP) * WP;
        for (int i = tid; i < HROWS * 66; i += 256) {
            int xr = i / 66, xc = i % 66;
            int gy = y0 + xr, gx = x0 + xc;
            sxu[i] = (gy < HP && gx < WP) ? f2bf(xs[(size_t)gy * WP + gx]) : (u16)0;
        }
    }
    __syncthreads();

    float bv[4];
    #pragma unroll
    for (int nt = 0; nt < 4; ++nt) bv[nt] = bias[nt * 16 + (l & 15)];

    f32x4 acc[TY][4];
    #pragma unroll
    for (int m = 0; m < TY; ++m)
        #pragma unroll
        for (int nt = 0; nt < 4; ++nt)
            acc[m][nt] = (f32x4){bv[nt], bv[nt], bv[nt], bv[nt]};

    const int xl   = l & 15;
    const int ci0  = ((l >> 4) & 1) * 8;
    const bool hiH = (l >= 32);
    const int wx   = wv_ * 16 + xl;

    // chunks 0..3: recurrent taps (tap = 2q + lane-half)
    #pragma unroll 1
    for (int q = 0; q < 4; ++q) {
        bf16x8 Bh[4], Bl[4];
        #pragma unroll
        for (int nt = 0; nt < 4; ++nt) {
            Bh[nt] = *(const bf16x8*)&sh_B[(((q * 4 + nt) * 2 + 0) * 64 + l) * 8];
            Bl[nt] = *(const bf16x8*)&sh_B[(((q * 4 + nt) * 2 + 1) * 64 + l) * 8];
        }
        const int tap = 2 * q + (hiH ? 1 : 0);
        const int dy = tap / 3, dx = tap - 3 * dy;
        #pragma unroll
        for (int m = 0; m < TY; ++m) {
            const int off = ((m + dy) * 66 + wx + dx) * HPITCH + ci0;
            bf16x8 Ah = *(const bf16x8*)&sh_h[off];
            bf16x8 Al = *(const bf16x8*)&sh_h[off + 16];
            #pragma unroll
            for (int nt = 0; nt < 4; ++nt) {
                acc[m][nt] = __builtin_amdgcn_mfma_f32_16x16x32_bf16(Ah, Bh[nt], acc[m][nt], 0, 0, 0);
                acc[m][nt] = __builtin_amdgcn_mfma_f32_16x16x32_bf16(Ah, Bl[nt], acc[m][nt], 0, 0, 0);
                acc[m][nt] = __builtin_amdgcn_mfma_f32_16x16x32_bf16(Al, Bh[nt], acc[m][nt], 0, 0, 0);
            }
        }
    }
    // chunk 4: lanes<32 = h tap8; lanes 32..47 = x taps 0..7; 48..63 = x tap8 + zeros
    {
        bf16x8 Bh[4], Bl[4];
        #pragma unroll
        for (int nt = 0; nt < 4; ++nt) {
            Bh[nt] = *(const bf16x8*)&sh_B[(((16 + nt) * 2 + 0) * 64 + l) * 8];
            Bl[nt] = *(const bf16x8*)&sh_B[(((16 + nt) * 2 + 1) * 64 + l) * 8];
        }
        #pragma unroll
        for (int m = 0; m < TY; ++m) {
            bf16x8 Ah, Al;
            if (!hiH) {
                const int off = ((m + 2) * 66 + wx + 2) * HPITCH + ci0;
                Ah = *(const bf16x8*)&sh_h[off];
                Al = *(const bf16x8*)&sh_h[off + 16];
            } else {
                u16 u[8];
                if (l < 48) {
                    #pragma unroll
                    for (int j = 0; j < 8; ++j)
                        u[j] = sxu[(m + j / 3) * 66 + wx + (j % 3)];
                } else {
                    u[0] = sxu[(m + 2) * 66 + wx + 2];
                    #pragma unroll
                    for (int j = 1; j < 8; ++j) u[j] = 0;
                }
                int4 p;
                p.x = (int)((u32)u[0] | ((u32)u[1] << 16));
                p.y = (int)((u32)u[2] | ((u32)u[3] << 16));
                p.z = (int)((u32)u[4] | ((u32)u[5] << 16));
                p.w = (int)((u32)u[6] | ((u32)u[7] << 16));
                Ah = __builtin_bit_cast(bf16x8, p);
                Al = __builtin_bit_cast(bf16x8, make_int4(0, 0, 0, 0));
            }
            #pragma unroll
            for (int nt = 0; nt < 4; ++nt) {
                acc[m][nt] = __builtin_amdgcn_mfma_f32_16x16x32_bf16(Ah, Bh[nt], acc[m][nt], 0, 0, 0);
                acc[m][nt] = __builtin_amdgcn_mfma_f32_16x16x32_bf16(Ah, Bl[nt], acc[m][nt], 0, 0, 0);
                acc[m][nt] = __builtin_amdgcn_mfma_f32_16x16x32_bf16(Al, Bh[nt], acc[m][nt], 0, 0, 0);
            }
        }
    }

    // gates + state update. C layout: col = l&15 (channel), row = (l>>4)*4 + r (x offset).
    const int ch = l & 15;
    #pragma unroll
    for (int m = 0; m < TY; ++m) {
        const int y = y0 + m;
        if (y < HO) {
            #pragma unroll
            for (int r = 0; r < 4; ++r) {
                const int x = x0 + wv_ * 16 + (l >> 4) * 4 + r;
                if (x < WO) {
                    size_t px = ((size_t)b * HO + y) * WO + x;
                    size_t gc = px * 16 + ch;
                    float co = (t > 0) ? cbuf[gc] : 0.0f;
                    float zi = acc[m][0][r], zf = acc[m][1][r], zc = acc[m][2][r], zo = acc[m][3][r];
                    float cn = fmaf(hsg(zf), co, hsg(zi) * tanh_fast(zc));
                    float hn = hsg(zo) * tanh_fast(cn);
                    cbuf[gc] = cn;
                    u16 uhi = f2bf(hn);
                    hout[px * 32 + ch]      = uhi;
                    hout[px * 32 + 16 + ch] = f2bf(hn - bf2f(uhi));
                }
            }
        }
    }
}

// ---------------- dense ----------------
#define NPX    (HO * WO)                       // 75,684 pixels
#define PCHUNK 512
#define NCHUNK ((NPX + PCHUNK - 1) / PCHUNK)   // 148

__device__ __forceinline__ float dotbf(u32 a, u32 c, const float* wp, float s) {
    float h0 = __uint_as_float(a << 16)          + __uint_as_float(c << 16);
    float h1 = __uint_as_float(a & 0xFFFF0000u)  + __uint_as_float(c & 0xFFFF0000u);
    s = fmaf(h0, wp[0], s);
    return fmaf(h1, wp[1], s);
}

__global__ void dense1(const u16* __restrict__ h, const float* __restrict__ w,
                       float* __restrict__ partial) {
    int b = blockIdx.y, tid = threadIdx.x;
    const u16* hb = h + (size_t)b * NPX * 32;
    float s = 0.0f;
    #pragma unroll
    for (int pp = 0; pp < 2; ++pp) {
        int px = blockIdx.x * PCHUNK + tid * 2 + pp;
        if (px < NPX) {
            const int4* g = (const int4*)&hb[(size_t)px * 32];
            int4 a0 = g[0], a1 = g[1], b0 = g[2], b1 = g[3];
            const float* wp = &w[(size_t)px * 16];
            s = dotbf((u32)a0.x, (u32)b0.x, wp + 0,  s);
            s = dotbf((u32)a0.y, (u32)b0.y, wp + 2,  s);
            s = dotbf((u32)a0.z, (u32)b0.z, wp + 4,  s);
            s = dotbf((u32)a0.w, (u32)b0.w, wp + 6,  s);
            s = dotbf((u32)a1.x, (u32)b1.x, wp + 8,  s);
            s = dotbf((u32)a1.y, (u32)b1.y, wp + 10, s);
            s = dotbf((u32)a1.z, (u32)b1.z, wp + 12, s);
            s = dotbf((u32)a1.w, (u32)b1.w, wp + 14, s);
        }
    }
    #pragma unroll
    for (int o = 32; o > 0; o >>= 1) s += __shfl_down(s, o, 64);
    __shared__ float red[4];
    if ((tid & 63) == 0) red[tid >> 6] = s;
    __syncthreads();
    if (tid == 0) partial[b * NCHUNK + blockIdx.x] = red[0] + red[1] + red[2] + red[3];
}

__global__ void dense2(const float* __restrict__ partial, const float* __restrict__ db,
                       float* __restrict__ out) {
    int b = blockIdx.x, tid = threadIdx.x;
    float s = 0.0f;
    for (int i = tid; i < NCHUNK; i += 256) s += partial[b * NCHUNK + i];
    #pragma unroll
    for (int o = 32; o > 0; o >>= 1) s += __shfl_down(s, o, 64);
    __shared__ float red[4];
    if ((tid & 63) == 0) red[tid >> 6] = s;
    __syncthreads();
    if (tid == 0) out[b] = red[0] + red[1] + red[2] + red[3] + db[0];
}

extern "C" void kernel_launch(void* const* d_in, const int* in_sizes, int n_in,
                              void* d_out, int out_size, void* d_ws, size_t ws_size,
                              hipStream_t stream) {
    const float* inputs = (const float*)d_in[0];
    const float* kin    = (const float*)d_in[1];
    const float* krec   = (const float*)d_in[2];
    const float* bias   = (const float*)d_in[3];
    const float* dw     = (const float*)d_in[4];
    const float* db     = (const float*)d_in[5];
    float* out = (float*)d_out;

    const size_t XPN = (size_t)B_ * T_ * HP * WP;       // 9,830,400 f32
    const size_t HN2 = (size_t)B_ * HO * WO * 32;       // interleaved h elems (u16)

    float* xp   = (float*)d_ws;
    u16*   h0   = (u16*)(xp + XPN);
    u16*   h1   = h0 + HN2;
    float* cbuf = (float*)(h1 + HN2);
    int4*  frag = (int4*)(cbuf + (HN2 / 2));            // 40 KB
    float* part = (float*)(frag + 40 * 64);

    {
        int total = B_ * T_ * HP * (WP / 2);
        pool_kernel<<<(total + 255) / 256, 256, 0, stream>>>(inputs, xp);
    }
    frag_build<<<10, 256, 0, stream>>>(krec, kin, frag);

    dim3 grid(4, (HO + TY - 1) / TY, B_);   // 4 x 80 x 8
    for (int t = 0; t < T_; ++t) {
        const u16* hi = (t & 1) ? h1 : h0;
        u16*       ho = (t & 1) ? h0 : h1;
        lstm_step<<<grid, 256, 0, stream>>>(xp, t, hi, ho, cbuf, frag, bias);
    }
    // t=15 (odd) wrote h0
    dense1<<<dim3(NCHUNK, B_), 256, 0, stream>>>(h0, dw, part);
    dense2<<<B_, 256, 0, stream>>>(part, db, out);
}

// Round 4
// 769.161 us; speedup vs baseline: 3.9443x; 1.4879x over previous
//
#include <hip/hip_runtime.h>
#include <hip/hip_bf16.h>
#include <cstdint>

#define B_  8
#define T_  16
#define HIN 640
#define WIN 480
#define HP  320
#define WP  240
#define HO  318
#define WO  238

typedef unsigned short u16;
typedef unsigned int   u32;
typedef __attribute__((ext_vector_type(8))) short bf16x8;
typedef __attribute__((ext_vector_type(4))) float f32x4;

#define TY    4
#define PITCH 24   // halfwords per pixel slot (48 B): b128-aligned, 12-dword stride -> ~2-way banks
#define NFRAG 25   // 20 hi (q0..4 x nt0..3) + 5 lo (nt=2 only, q0..4)

__device__ __forceinline__ u16 f2bf(float f) {          // RNE float->bf16 bits
    u32 u = __float_as_uint(f);
    return (u16)((u + 0x7fffu + ((u >> 16) & 1u)) >> 16);
}
__device__ __forceinline__ float bf2f(u16 u) {
    return __uint_as_float(((u32)u) << 16);
}
__device__ __forceinline__ float hsg(float v) {
    return fminf(fmaxf(fmaf(v, 0.2f, 0.5f), 0.0f), 1.0f);
}
__device__ __forceinline__ float tanh_fast(float x) {
    float ax = fminf(fabsf(x), 12.0f);
    float e  = __expf(2.0f * ax);
    float t  = 1.0f - __fdividef(2.0f, e + 1.0f);
    return copysignf(t, x);
}

// ---------------- MaxPool (1,2,2) -> bf16 ----------------
__global__ void pool_kernel(const float* __restrict__ in, u32* __restrict__ out) {
    int idx = blockIdx.x * 256 + threadIdx.x;
    const int total = B_ * T_ * HP * (WP / 2);
    if (idx >= total) return;
    int xp   = idx % (WP / 2);
    int rest = idx / (WP / 2);
    int y    = rest % HP;
    int bt   = rest / HP;
    const float* src = in + ((size_t)bt * HIN + 2 * y) * WIN + xp * 4;
    float4 a = *(const float4*)src;
    float4 b = *(const float4*)(src + WIN);
    float m0 = fmaxf(fmaxf(a.x, a.y), fmaxf(b.x, b.y));
    float m1 = fmaxf(fmaxf(a.z, a.w), fmaxf(b.z, b.w));
    out[((size_t)bt * HP + y) * (WP / 2) + xp] = (u32)f2bf(m0) | ((u32)f2bf(m1) << 16);
}

// ---------------- weight fragment pre-pack ----------------
// K layout: k = tap*16+ci (k<144 recurrent), k = 144+xtap (k<153 input conv), else 0.
// Frags 0..19: hi plane, f = q*4+nt. Frags 20..24: lo plane of nt=2 (z_c gate), f = 20+q.
// B-frag (16x16x32): lane l holds W[k = q*32 + (l>>4)*8 + j][n = nt*16 + (l&15)], j=0..7.
__global__ void frag_build(const float* __restrict__ krec, const float* __restrict__ kin,
                           int4* __restrict__ fragbuf) {
    int idx = blockIdx.x * 256 + threadIdx.x;
    if (idx >= NFRAG * 64) return;
    int l = idx & 63, f = idx >> 6;
    int lo = (f >= 20);
    int q  = lo ? (f - 20) : (f >> 2);
    int nt = lo ? 2 : (f & 3);
    int n = nt * 16 + (l & 15), o = l >> 4;
    u16 u[8];
    #pragma unroll
    for (int j = 0; j < 8; ++j) {
        int k = q * 32 + o * 8 + j;
        float wv = 0.0f;
        if (k < 144) wv = krec[k * 64 + n];
        else if (k < 153) wv = kin[(k - 144) * 64 + n];
        u16 hi = f2bf(wv);
        u[j] = lo ? f2bf(wv - bf2f(hi)) : hi;
    }
    int4 v;
    v.x = (int)((u32)u[0] | ((u32)u[1] << 16));
    v.y = (int)((u32)u[2] | ((u32)u[3] << 16));
    v.z = (int)((u32)u[4] | ((u32)u[5] << 16));
    v.w = (int)((u32)u[6] | ((u32)u[7] << 16));
    fragbuf[f * 64 + l] = v;
}

// ---------------- fused ConvLSTM step ----------------
// Tile: TY=4 rows x 64 x. 4 waves; wave w owns x-slice w*16..+15, all rows, all 4 gates.
// Passes: z = h_bf16 * (w_hi + [nt==2] w_lo) + x_bf16 * (same), h exact-as-stored.
__global__ __launch_bounds__(256, 3)
void lstm_step(const u16* __restrict__ xpb, int t,
               const u16* __restrict__ hin,    // [b][y][x][16] bf16
               u16* __restrict__ hout,
               float* __restrict__ cbuf,
               const int4* __restrict__ fragbuf,
               const float* __restrict__ bias) {
    __shared__ __align__(16) u16 sh_h[6 * 66 * PITCH];   // 19,008 B
    __shared__ __align__(16) u16 sh_B[NFRAG * 64 * 8];   // 25,600 B
    __shared__ __align__(16) u16 sxf[2 * 256 * 8];       //  8,192 B  (total 52,800 B)

    const int tid = threadIdx.x;
    const int wv_ = tid >> 6;
    const int l   = tid & 63;
    const int b   = blockIdx.z;
    const int y0  = blockIdx.y * TY;
    const int x0  = blockIdx.x * 64;

    // stage B fragments (25.6 KB, L2-hot)
    for (int i = tid; i < NFRAG * 64; i += 256)
        ((int4*)sh_B)[i] = fragbuf[i];
    // stage h halo (single bf16 plane, 32 B/pixel)
    for (int i = tid; i < 6 * 66; i += 256) {
        int hr = i / 66, hx = i % 66;
        int gy = y0 - 1 + hr, gx = x0 - 1 + hx;
        bool ok = (t > 0) && gy >= 0 && gy < HO && gx >= 0 && gx < WO;
        int4 v0 = make_int4(0, 0, 0, 0), v1 = v0;
        if (ok) {
            const int4* g = (const int4*)&hin[(((size_t)b * HO + gy) * WO + gx) * 16];
            v0 = g[0]; v1 = g[1];
        }
        u16* d = &sh_h[i * PITCH];
        *(int4*)d = v0; *(int4*)(d + 8) = v1;
    }
    // pack x A-fragments: slot tid = (m = tid>>6, sxi = tid&63). Taps 0..7 -> sxf[0], tap 8 -> sxf[1].
    {
        const int sxi = tid & 63, m = tid >> 6;
        const u16* xs = xpb + (size_t)(b * T_ + t) * HP * WP;
        u16 u[9];
        #pragma unroll
        for (int j = 0; j < 9; ++j) {
            int gy = y0 + m + j / 3, gx = x0 + sxi + j % 3;
            u[j] = (gy < HP && gx < WP) ? xs[(size_t)gy * WP + gx] : (u16)0;
        }
        int4 p;
        p.x = (int)((u32)u[0] | ((u32)u[1] << 16));
        p.y = (int)((u32)u[2] | ((u32)u[3] << 16));
        p.z = (int)((u32)u[4] | ((u32)u[5] << 16));
        p.w = (int)((u32)u[6] | ((u32)u[7] << 16));
        *(int4*)&sxf[tid * 8] = p;
        *(int4*)&sxf[(256 + tid) * 8] = make_int4((int)(u32)u[8], 0, 0, 0);
    }
    __syncthreads();

    float bv[4];
    #pragma unroll
    for (int nt = 0; nt < 4; ++nt) bv[nt] = bias[nt * 16 + (l & 15)];

    f32x4 acc[TY][4];
    #pragma unroll
    for (int m = 0; m < TY; ++m)
        #pragma unroll
        for (int nt = 0; nt < 4; ++nt)
            acc[m][nt] = (f32x4){bv[nt], bv[nt], bv[nt], bv[nt]};

    const int xl   = l & 15;
    const int o    = l >> 4;
    const int ci0  = (o & 1) * 8;
    const bool hiH = (l >= 32);
    const int wx   = wv_ * 16 + xl;

    // chunks 0..3: recurrent taps 0..7 (tap = 2q + lane-half)
    #pragma unroll 1
    for (int q = 0; q < 4; ++q) {
        bf16x8 Bh[4], Bl2;
        #pragma unroll
        for (int nt = 0; nt < 4; ++nt)
            Bh[nt] = *(const bf16x8*)&sh_B[((q * 4 + nt) * 64 + l) * 8];
        Bl2 = *(const bf16x8*)&sh_B[((20 + q) * 64 + l) * 8];
        const int tap = 2 * q + (hiH ? 1 : 0);
        const int dy = tap / 3, dx = tap - 3 * dy;
        #pragma unroll
        for (int m = 0; m < TY; ++m) {
            bf16x8 Ah = *(const bf16x8*)&sh_h[((m + dy) * 66 + wx + dx) * PITCH + ci0];
            acc[m][0] = __builtin_amdgcn_mfma_f32_16x16x32_bf16(Ah, Bh[0], acc[m][0], 0, 0, 0);
            acc[m][1] = __builtin_amdgcn_mfma_f32_16x16x32_bf16(Ah, Bh[1], acc[m][1], 0, 0, 0);
            acc[m][2] = __builtin_amdgcn_mfma_f32_16x16x32_bf16(Ah, Bh[2], acc[m][2], 0, 0, 0);
            acc[m][2] = __builtin_amdgcn_mfma_f32_16x16x32_bf16(Ah, Bl2,   acc[m][2], 0, 0, 0);
            acc[m][3] = __builtin_amdgcn_mfma_f32_16x16x32_bf16(Ah, Bh[3], acc[m][3], 0, 0, 0);
        }
    }
    // chunk 4: lanes o=0,1 -> rec tap8 (ci 0..15); o=2 -> x taps 0..7; o=3 -> x tap8 + zeros
    {
        bf16x8 Bh[4], Bl2;
        #pragma unroll
        for (int nt = 0; nt < 4; ++nt)
            Bh[nt] = *(const bf16x8*)&sh_B[((16 + nt) * 64 + l) * 8];
        Bl2 = *(const bf16x8*)&sh_B[(24 * 64 + l) * 8];
        #pragma unroll
        for (int m = 0; m < TY; ++m) {
            bf16x8 Ah;
            if (!hiH) {
                Ah = *(const bf16x8*)&sh_h[((m + 2) * 66 + wx + 2) * PITCH + ci0];
            } else {
                const int slot = (o == 2 ? 0 : 256) + m * 64 + wx;
                Ah = *(const bf16x8*)&sxf[slot * 8];
            }
            acc[m][0] = __builtin_amdgcn_mfma_f32_16x16x32_bf16(Ah, Bh[0], acc[m][0], 0, 0, 0);
            acc[m][1] = __builtin_amdgcn_mfma_f32_16x16x32_bf16(Ah, Bh[1], acc[m][1], 0, 0, 0);
            acc[m][2] = __builtin_amdgcn_mfma_f32_16x16x32_bf16(Ah, Bh[2], acc[m][2], 0, 0, 0);
            acc[m][2] = __builtin_amdgcn_mfma_f32_16x16x32_bf16(Ah, Bl2,   acc[m][2], 0, 0, 0);
            acc[m][3] = __builtin_amdgcn_mfma_f32_16x16x32_bf16(Ah, Bh[3], acc[m][3], 0, 0, 0);
        }
    }

    // gates + state update. C layout: col = l&15 (channel), row = (l>>4)*4 + r (x offset).
    const int ch = l & 15;
    #pragma unroll
    for (int m = 0; m < TY; ++m) {
        const int y = y0 + m;
        if (y < HO) {
            #pragma unroll
            for (int r = 0; r < 4; ++r) {
                const int x = x0 + wv_ * 16 + (l >> 4) * 4 + r;
                if (x < WO) {
                    size_t px = ((size_t)b * HO + y) * WO + x;
                    size_t gc = px * 16 + ch;
                    float co = (t > 0) ? cbuf[gc] : 0.0f;
                    float zi = acc[m][0][r], zf = acc[m][1][r], zc = acc[m][2][r], zo = acc[m][3][r];
                    float cn = fmaf(hsg(zf), co, hsg(zi) * tanh_fast(zc));
                    float hn = hsg(zo) * tanh_fast(cn);
                    cbuf[gc] = cn;
                    hout[gc] = f2bf(hn);
                }
            }
        }
    }
}

// ---------------- dense ----------------
#define NPX    (HO * WO)                       // 75,684 pixels
#define PCHUNK 512
#define NCHUNK ((NPX + PCHUNK - 1) / PCHUNK)   // 148

__device__ __forceinline__ float dot2(u32 a, float w0, float w1, float s) {
    s = fmaf(bf2f((u16)a), w0, s);
    return fmaf(bf2f((u16)(a >> 16)), w1, s);
}

__global__ void dense1(const u16* __restrict__ h, const float* __restrict__ w,
                       float* __restrict__ partial) {
    int b = blockIdx.y, tid = threadIdx.x;
    const u16* hb = h + (size_t)b * NPX * 16;
    float s = 0.0f;
    #pragma unroll
    for (int pp = 0; pp < 2; ++pp) {
        int px = blockIdx.x * PCHUNK + tid * 2 + pp;
        if (px < NPX) {
            const int4* g = (const int4*)&hb[(size_t)px * 16];
            int4 a0 = g[0], a1 = g[1];
            const float* wp = &w[(size_t)px * 16];
            s = dot2((u32)a0.x, wp[0],  wp[1],  s);
            s = dot2((u32)a0.y, wp[2],  wp[3],  s);
            s = dot2((u32)a0.z, wp[4],  wp[5],  s);
            s = dot2((u32)a0.w, wp[6],  wp[7],  s);
            s = dot2((u32)a1.x, wp[8],  wp[9],  s);
            s = dot2((u32)a1.y, wp[10], wp[11], s);
            s = dot2((u32)a1.z, wp[12], wp[13], s);
            s = dot2((u32)a1.w, wp[14], wp[15], s);
        }
    }
    #pragma unroll
    for (int o = 32; o > 0; o >>= 1) s += __shfl_down(s, o, 64);
    __shared__ float red[4];
    if ((tid & 63) == 0) red[tid >> 6] = s;
    __syncthreads();
    if (tid == 0) partial[b * NCHUNK + blockIdx.x] = red[0] + red[1] + red[2] + red[3];
}

__global__ void dense2(const float* __restrict__ partial, const float* __restrict__ db,
                       float* __restrict__ out) {
    int b = blockIdx.x, tid = threadIdx.x;
    float s = 0.0f;
    for (int i = tid; i < NCHUNK; i += 256) s += partial[b * NCHUNK + i];
    #pragma unroll
    for (int o = 32; o > 0; o >>= 1) s += __shfl_down(s, o, 64);
    __shared__ float red[4];
    if ((tid & 63) == 0) red[tid >> 6] = s;
    __syncthreads();
    if (tid == 0) out[b] = red[0] + red[1] + red[2] + red[3] + db[0];
}

extern "C" void kernel_launch(void* const* d_in, const int* in_sizes, int n_in,
                              void* d_out, int out_size, void* d_ws, size_t ws_size,
                              hipStream_t stream) {
    const float* inputs = (const float*)d_in[0];
    const float* kin    = (const float*)d_in[1];
    const float* krec   = (const float*)d_in[2];
    const float* bias   = (const float*)d_in[3];
    const float* dw     = (const float*)d_in[4];
    const float* db     = (const float*)d_in[5];
    float* out = (float*)d_out;

    const size_t XPN = (size_t)B_ * T_ * HP * WP;   // 9,830,400 u16 (bf16 pooled x)
    const size_t HN  = (size_t)B_ * HO * WO * 16;   // 9,687,552 u16 per h buffer

    u16*   xp   = (u16*)d_ws;
    u16*   h0   = xp + XPN;
    u16*   h1   = h0 + HN;
    float* cbuf = (float*)(h1 + HN);
    int4*  frag = (int4*)(cbuf + HN);               // 25,600 B
    float* part = (float*)(frag + NFRAG * 64);

    {
        int total = B_ * T_ * HP * (WP / 2);
        pool_kernel<<<(total + 255) / 256, 256, 0, stream>>>(inputs, (u32*)xp);
    }
    frag_build<<<(NFRAG * 64 + 255) / 256, 256, 0, stream>>>(krec, kin, frag);

    dim3 grid(4, (HO + TY - 1) / TY, B_);   // 4 x 80 x 8
    for (int t = 0; t < T_; ++t) {
        const u16* hi = (t & 1) ? h1 : h0;
        u16*       ho = (t & 1) ? h0 : h1;
        lstm_step<<<grid, 256, 0, stream>>>(xp, t, hi, ho, cbuf, frag, bias);
    }
    // t=15 (odd) wrote h0
    dense1<<<dim3(NCHUNK, B_), 256, 0, stream>>>(h0, dw, part);
    dense2<<<B_, 256, 0, stream>>>(part, db, out);
}